// Round 1
// baseline (410.720 us; speedup 1.0000x reference)
//
#include <hip/hip_runtime.h>

using u32 = unsigned int;

// ---- workspace layout (u32 words) ----
#define H1_BINS 4096   // bits [30:19]  (12 bits)
#define H2_BINS 2048   // bits [18:8]   (11 bits)
#define H3_BINS 256    // bits [7:0]    (8 bits)
#define H1_OFF  0
#define H2_OFF  (H1_OFF + 2 * H1_BINS)       // 8192
#define H3_OFF  (H2_OFF + 2 * H2_BINS)       // 12288
#define SEL_OFF (H3_OFF + 2 * H3_BINS)       // 12800
#define SEL_WORDS 8
// sel fields per matrix: 0=p1, 1=p2, 2=G1, 3=t(threshold bits), 4=R, 5=G12, 6=eqcnt, 7=compact cnt
#define CTR_OFF (SEL_OFF + 2 * SEL_WORDS)    // 12816  done-counters: [0,1]=h1 [2,3]=h2 [4,5]=h3
#define CTR_WORDS 8
#define EQ_OFF  (CTR_OFF + CTR_WORDS)        // 12824
#define EQ_CAP  4096
#define ZERO_WORDS EQ_OFF                    // zero hists + sel + ctrs; eqlist needs no init

#define CBUF 2048                            // per-block compaction staging (LDS)

__device__ __forceinline__ u32 absbits(u32 x) { return x & 0x7FFFFFFFu; }

// ---------- in-kernel select (runs in the LAST block of each hist kernel) ----------
// Reads the global histogram via atomicAdd(p,0) RMWs (coherent-point reads, safe
// cross-XCD). Suffix-scan from the top bin; exactly one thread writes the result.
template<int BINS>
__device__ void tail_select(u32* __restrict__ gh, u32 K, int pass,
                            u32* __restrict__ sel, u32* __restrict__ sh /*>=256*/) {
    constexpr int C = BINS / 256;
    const int tid = threadIdx.x;
    u32 Gprev = 0;
    if (pass == 1) Gprev = sel[2];
    else if (pass == 2) Gprev = sel[5];
    const u32 Krem = K - Gprev;   // #largest still needed within current prefix

    u32 loc[C];
    u32 s = 0;
    const int base = tid * C;
#pragma unroll
    for (int i = 0; i < C; i++) { loc[i] = atomicAdd(&gh[base + i], 0u); s += loc[i]; }
    sh[tid] = s;
    __syncthreads();
    if (tid == 0) {               // suffix sums over 256 chunk totals
        u32 run = 0;
        for (int i = 255; i >= 0; i--) { u32 x = sh[i]; sh[i] = run; run += x; }
    }
    __syncthreads();
    u32 running = sh[tid];        // count of elements in bins above this chunk
#pragma unroll
    for (int b = C - 1; b >= 0; b--) {
        u32 c = loc[b];
        if (running < Krem && running + c >= Krem) {  // exactly one (bin) satisfies
            int bin = base + b;
            if (pass == 0)      { sel[0] = (u32)bin; sel[2] = running; }
            else if (pass == 1) { sel[1] = (u32)bin; sel[5] = Gprev + running; }
            else {
                sel[3] = (sel[0] << 19) | (sel[1] << 8) | (u32)bin;  // threshold bits t
                sel[4] = Krem - running;                             // R = ones among ties
            }
        }
        running += c;
    }
}

// ---------- pass 1: hist of bits [30:19]; last block selects p1 ----------
__global__ void k_hist1(const float* __restrict__ in0, const float* __restrict__ in1,
                        int n0, int n1, int K0, int K1, u32* __restrict__ ws) {
    __shared__ u32 h[H1_BINS];
    __shared__ u32 isLast;
    const int m = blockIdx.y;
    const u32* in = (const u32*)(m ? in1 : in0);
    const int n = m ? n1 : n0;
    const int n4 = n >> 2;
    for (int i = threadIdx.x; i < H1_BINS; i += blockDim.x) h[i] = 0;
    __syncthreads();
    const uint4* v = (const uint4*)in;
    const int stride = gridDim.x * blockDim.x;
    for (int i = blockIdx.x * blockDim.x + threadIdx.x; i < n4; i += stride) {
        uint4 x = v[i];
        atomicAdd(&h[absbits(x.x) >> 19], 1u);
        atomicAdd(&h[absbits(x.y) >> 19], 1u);
        atomicAdd(&h[absbits(x.z) >> 19], 1u);
        atomicAdd(&h[absbits(x.w) >> 19], 1u);
    }
    if (blockIdx.x == 0 && (int)threadIdx.x < (n & 3)) {   // tail (unused for 4-divisible n)
        u32 u = absbits(in[n4 * 4 + threadIdx.x]);
        atomicAdd(&h[u >> 19], 1u);
    }
    __syncthreads();
    u32* g = ws + H1_OFF + m * H1_BINS;
    for (int i = threadIdx.x; i < H1_BINS; i += blockDim.x)
        if (h[i]) atomicAdd(&g[i], h[i]);
    __syncthreads();                       // barrier drains vmcnt: flush RMWs complete
    if (threadIdx.x == 0) {
        __threadfence();
        u32 d = atomicAdd(&ws[CTR_OFF + 0 + m], 1u);
        isLast = (d == gridDim.x - 1) ? 1u : 0u;
    }
    __syncthreads();
    if (isLast) {
        u32* sel = ws + SEL_OFF + m * SEL_WORDS;
        tail_select<H1_BINS>(g, (u32)(m ? K1 : K0), 0, sel, h);
    }
}

// ---------- pass 2: hist of bits [18:8] among prefix==p1, plus COMPACTION of
// matching absbits into scratch (the output buffer, overwritten later by k_mask).
// Last block selects p2. ----------
__global__ void k_hist2(const float* __restrict__ in0, const float* __restrict__ in1,
                        u32* __restrict__ sc0, u32* __restrict__ sc1,
                        int n0, int n1, int K0, int K1, u32* __restrict__ ws) {
    __shared__ u32 h[H2_BINS];
    __shared__ u32 lbuf[CBUF];
    __shared__ u32 lcnt;
    __shared__ u32 gbase;
    __shared__ u32 isLast;
    const int m = blockIdx.y;
    const u32* in = (const u32*)(m ? in1 : in0);
    u32* scr = m ? sc1 : sc0;
    const int n = m ? n1 : n0;
    const int n4 = n >> 2;
    u32* sel = ws + SEL_OFF + m * SEL_WORDS;
    const u32 p1 = sel[0];
    for (int i = threadIdx.x; i < H2_BINS; i += blockDim.x) h[i] = 0;
    if (threadIdx.x == 0) lcnt = 0;
    __syncthreads();
    const uint4* v = (const uint4*)in;
    const int stride = gridDim.x * blockDim.x;
    const int i0 = blockIdx.x * blockDim.x + threadIdx.x;
    const int nIter = (n4 + stride - 1) / stride;   // uniform across block
    for (int it = 0; it < nIter; ++it) {
        int i = i0 + it * stride;
        if (i < n4) {
            uint4 x = v[i];
            u32 a;
            a = absbits(x.x); if ((a >> 19) == p1) { atomicAdd(&h[(a >> 8) & 0x7FFu], 1u); u32 p = atomicAdd(&lcnt, 1u); lbuf[p] = a; }
            a = absbits(x.y); if ((a >> 19) == p1) { atomicAdd(&h[(a >> 8) & 0x7FFu], 1u); u32 p = atomicAdd(&lcnt, 1u); lbuf[p] = a; }
            a = absbits(x.z); if ((a >> 19) == p1) { atomicAdd(&h[(a >> 8) & 0x7FFu], 1u); u32 p = atomicAdd(&lcnt, 1u); lbuf[p] = a; }
            a = absbits(x.w); if ((a >> 19) == p1) { atomicAdd(&h[(a >> 8) & 0x7FFu], 1u); u32 p = atomicAdd(&lcnt, 1u); lbuf[p] = a; }
        }
        __syncthreads();
        if (lcnt >= CBUF - 1024) {   // max growth per iter = 256*4; invariant: never overflows
            u32 c = lcnt;
            if (threadIdx.x == 0) gbase = atomicAdd(&sel[7], c);
            __syncthreads();
            for (u32 j = threadIdx.x; j < c; j += blockDim.x) scr[gbase + j] = lbuf[j];
            __syncthreads();
            if (threadIdx.x == 0) lcnt = 0;
            __syncthreads();
        }
    }
    if (blockIdx.x == 0 && (int)threadIdx.x < (n & 3)) {   // scalar tail (rare path)
        u32 a = absbits(in[n4 * 4 + threadIdx.x]);
        if ((a >> 19) == p1) {
            atomicAdd(&h[(a >> 8) & 0x7FFu], 1u);
            u32 p = atomicAdd(&sel[7], 1u);   // disjoint reservation vs block flushes
            scr[p] = a;
        }
    }
    __syncthreads();
    {   // final flush
        u32 c = lcnt;
        if (c) {
            if (threadIdx.x == 0) gbase = atomicAdd(&sel[7], c);
            __syncthreads();
            for (u32 j = threadIdx.x; j < c; j += blockDim.x) scr[gbase + j] = lbuf[j];
        }
    }
    __syncthreads();
    u32* g = ws + H2_OFF + m * H2_BINS;
    for (int i = threadIdx.x; i < H2_BINS; i += blockDim.x)
        if (h[i]) atomicAdd(&g[i], h[i]);
    __syncthreads();
    if (threadIdx.x == 0) {
        __threadfence();
        u32 d = atomicAdd(&ws[CTR_OFF + 2 + m], 1u);
        isLast = (d == gridDim.x - 1) ? 1u : 0u;
    }
    __syncthreads();
    if (isLast) tail_select<H2_BINS>(g, (u32)(m ? K1 : K0), 1, sel, h);
}

// ---------- pass 3: hist of bits [7:0] over the COMPACTED list (~1% of data).
// Last block selects the final threshold t and tie count R. ----------
__global__ void k_hist3(const u32* __restrict__ sc0, const u32* __restrict__ sc1,
                        int K0, int K1, u32* __restrict__ ws) {
    __shared__ u32 h[H3_BINS];
    __shared__ u32 sh[256];
    __shared__ u32 isLast;
    const int m = blockIdx.y;
    const u32* scr = m ? sc1 : sc0;
    u32* sel = ws + SEL_OFF + m * SEL_WORDS;
    const u32 E = sel[7];
    const u32 pre20 = (sel[0] << 11) | sel[1];
    for (int i = threadIdx.x; i < H3_BINS; i += blockDim.x) h[i] = 0;
    __syncthreads();
    const u32 stride = gridDim.x * blockDim.x;
    for (u32 i = blockIdx.x * blockDim.x + threadIdx.x; i < E; i += stride) {
        u32 a = scr[i];
        if ((a >> 8) == pre20) atomicAdd(&h[a & 0xFFu], 1u);
    }
    __syncthreads();
    u32* g = ws + H3_OFF + m * H3_BINS;
    for (int i = threadIdx.x; i < H3_BINS; i += blockDim.x)
        if (h[i]) atomicAdd(&g[i], h[i]);
    __syncthreads();
    if (threadIdx.x == 0) {
        __threadfence();
        u32 d = atomicAdd(&ws[CTR_OFF + 4 + m], 1u);
        isLast = (d == gridDim.x - 1) ? 1u : 0u;
    }
    __syncthreads();
    if (isLast) tail_select<H3_BINS>(g, (u32)(m ? K1 : K0), 2, sel, sh);
}

// ---------- final mask write + collect tied indices ----------
__global__ void k_mask(const float* __restrict__ in0, const float* __restrict__ in1,
                       float* __restrict__ out0, float* __restrict__ out1,
                       int n0, int n1, u32* __restrict__ ws) {
    const int m = blockIdx.y;
    const u32* in = (const u32*)(m ? in1 : in0);
    float* out = m ? out1 : out0;
    const int n = m ? n1 : n0;
    const int n4 = n >> 2;
    u32* sel = ws + SEL_OFF + m * SEL_WORDS;
    const u32 t = sel[3];
    u32* eq = ws + EQ_OFF + m * EQ_CAP;
    const uint4* v = (const uint4*)in;
    float4* o = (float4*)out;
    const int stride = gridDim.x * blockDim.x;
    for (int i = blockIdx.x * blockDim.x + threadIdx.x; i < n4; i += stride) {
        uint4 x = v[i];
        u32 a0 = absbits(x.x), a1 = absbits(x.y), a2 = absbits(x.z), a3 = absbits(x.w);
        float4 r;
        r.x = (a0 > t) ? 1.0f : 0.0f;
        r.y = (a1 > t) ? 1.0f : 0.0f;
        r.z = (a2 > t) ? 1.0f : 0.0f;
        r.w = (a3 > t) ? 1.0f : 0.0f;
        o[i] = r;
        if (a0 == t) { u32 p = atomicAdd(&sel[6], 1u); if (p < EQ_CAP) eq[p] = (u32)(4 * i + 0); }
        if (a1 == t) { u32 p = atomicAdd(&sel[6], 1u); if (p < EQ_CAP) eq[p] = (u32)(4 * i + 1); }
        if (a2 == t) { u32 p = atomicAdd(&sel[6], 1u); if (p < EQ_CAP) eq[p] = (u32)(4 * i + 2); }
        if (a3 == t) { u32 p = atomicAdd(&sel[6], 1u); if (p < EQ_CAP) eq[p] = (u32)(4 * i + 3); }
    }
    if (blockIdx.x == 0 && (int)threadIdx.x < (n & 3)) {
        int idx = n4 * 4 + threadIdx.x;
        u32 a = absbits(in[idx]);
        out[idx] = (a > t) ? 1.0f : 0.0f;
        if (a == t) { u32 p = atomicAdd(&sel[6], 1u); if (p < EQ_CAP) eq[p] = (u32)idx; }
    }
}

// ---------- tie resolution: stable ascending argsort keeps later indices on top ----------
__global__ void k_tie(float* __restrict__ out0, float* __restrict__ out1, u32* __restrict__ ws) {
    const int m = blockIdx.x;
    float* out = m ? out1 : out0;
    u32* sel = ws + SEL_OFF + m * SEL_WORDS;
    u32 E = sel[6]; if (E > EQ_CAP) E = EQ_CAP;
    const u32 R = sel[4];
    const u32* eq = ws + EQ_OFF + m * EQ_CAP;
    for (u32 e = threadIdx.x; e < E; e += blockDim.x) {
        u32 idx = eq[e];
        u32 cnt = 0;
        for (u32 e2 = 0; e2 < E; e2++) cnt += (eq[e2] > idx) ? 1u : 0u;
        if (cnt < R) out[idx] = 1.0f;   // the R tied elements with largest indices get 1
    }
}

extern "C" void kernel_launch(void* const* d_in, const int* in_sizes, int n_in,
                              void* d_out, int out_size, void* d_ws, size_t ws_size,
                              hipStream_t stream) {
    const float* in0 = (const float*)d_in[0];
    const float* in1 = (const float*)d_in[1];
    const int n0 = in_sizes[0];
    const int n1 = in_sizes[1];
    float* out0 = (float*)d_out;
    float* out1 = out0 + n0;
    u32* ws = (u32*)d_ws;

    // Faithful to int((1.0 - k) * n) in double precision: j = 15,099,494 for n = 16,777,216
    const double k = 0.1;
    const int j0 = (int)((1.0 - k) * (double)n0);
    const int j1 = (int)((1.0 - k) * (double)n1);
    const int K0 = n0 - j0;   // number of ones = 1,677,722
    const int K1 = n1 - j1;

    // Compaction scratch lives in the output buffer: it is consumed by k_hist3
    // strictly before k_mask overwrites it. Capacity = n words per matrix (no overflow).
    u32* scr0 = (u32*)out0;
    u32* scr1 = (u32*)out1;

    hipMemsetAsync(ws, 0, ZERO_WORDS * sizeof(u32), stream);

    dim3 hgrid(1024, 2);
    k_hist1<<<hgrid, 256, 0, stream>>>(in0, in1, n0, n1, K0, K1, ws);
    k_hist2<<<hgrid, 256, 0, stream>>>(in0, in1, scr0, scr1, n0, n1, K0, K1, ws);
    k_hist3<<<dim3(32, 2), 256, 0, stream>>>(scr0, scr1, K0, K1, ws);
    k_mask<<<dim3(1024, 2), 256, 0, stream>>>(in0, in1, out0, out1, n0, n1, ws);
    k_tie<<<2, 256, 0, stream>>>(out0, out1, ws);
}

// Round 8
// 387.800 us; speedup vs baseline: 1.0591x; 1.0591x over previous
//
#include <hip/hip_runtime.h>

using u32 = unsigned int;
typedef float f32x4 __attribute__((ext_vector_type(4)));   // native vector for NT stores

// ---- workspace layout (u32 words) ----
#define H1_BINS 4096                         // bits [30:19] (12-bit prefix)
#define H1_OFF  0
#define SEL_OFF (H1_OFF + 2 * H1_BINS)       // 8192
#define SEL_WORDS 8
// sel fields per matrix: 0=p1, 2=G1(count strictly above bin p1), 3=t(threshold bits),
//                        4=R(ones among ties), 6=eq count, 7=compact count
#define CTR_OFF (SEL_OFF + 2 * SEL_WORDS)    // 8208: done-counters for k_hist1 [m]
#define EQ_OFF  (CTR_OFF + 8)                // 8216
#define EQ_CAP  4096
#define ZERO_WORDS EQ_OFF                    // zero hist + sel + ctr; eq list needs no init

#define CBUF    9216                         // compact staging words (36 KB LDS)
#define CTHRESH 1024                         // flush threshold; max growth/iter = 256*32 = 8192

__device__ __forceinline__ u32 absbits(u32 x) { return x & 0x7FFFFFFFu; }

// ---------- select p1 among 4096 bins (runs in LAST block of k_hist1) ----------
// Reads global hist via atomicAdd(p,0) RMWs (coherent-point reads, cross-XCD safe).
__device__ void select_p1(u32* __restrict__ gh, u32 K, u32* __restrict__ sel,
                          u32* __restrict__ sh /*>=256 words LDS*/) {
    const int tid = threadIdx.x;              // 256 threads
    u32 loc[16];
    u32 s = 0;
    const int base = tid * 16;
#pragma unroll
    for (int i = 0; i < 16; i++) { loc[i] = atomicAdd(&gh[base + i], 0u); s += loc[i]; }
    sh[tid] = s;
    __syncthreads();
    if (tid == 0) {                           // suffix sums over 256 chunk totals
        u32 run = 0;
        for (int i = 255; i >= 0; i--) { u32 x = sh[i]; sh[i] = run; run += x; }
    }
    __syncthreads();
    u32 running = sh[tid];                    // count in bins above this chunk
#pragma unroll
    for (int b = 15; b >= 0; b--) {
        u32 c = loc[b];
        if (running < K && running + c >= K) {   // exactly one bin satisfies
            sel[0] = (u32)(base + b);            // p1
            sel[2] = running;                    // G1 = count strictly above
        }
        running += c;
    }
}

// ---------- pass 1: 4096-bin hist of bits [30:19], 8-deep batched loads ----------
__global__ void k_hist1(const float* __restrict__ in0, const float* __restrict__ in1,
                        int n0, int n1, int K0, int K1, u32* __restrict__ ws) {
    __shared__ u32 h[H1_BINS];
    __shared__ u32 isLast;
    const int m = blockIdx.y;
    const u32* in = (const u32*)(m ? in1 : in0);
    const int n = m ? n1 : n0;
    const int n4 = n >> 2;
    for (int i = threadIdx.x; i < H1_BINS; i += blockDim.x) h[i] = 0;
    __syncthreads();
    const uint4* v = (const uint4*)in;
    const int stride = gridDim.x * blockDim.x;
    int i = blockIdx.x * blockDim.x + threadIdx.x;
    // 8 independent loads in flight per wave -> latency-hiding via MLP
    for (; i + 7 * stride < n4; i += 8 * stride) {
        uint4 x[8];
#pragma unroll
        for (int k = 0; k < 8; k++) x[k] = v[i + k * stride];
#pragma unroll
        for (int k = 0; k < 8; k++) {
            atomicAdd(&h[absbits(x[k].x) >> 19], 1u);
            atomicAdd(&h[absbits(x[k].y) >> 19], 1u);
            atomicAdd(&h[absbits(x[k].z) >> 19], 1u);
            atomicAdd(&h[absbits(x[k].w) >> 19], 1u);
        }
    }
    for (; i < n4; i += stride) {
        uint4 x = v[i];
        atomicAdd(&h[absbits(x.x) >> 19], 1u);
        atomicAdd(&h[absbits(x.y) >> 19], 1u);
        atomicAdd(&h[absbits(x.z) >> 19], 1u);
        atomicAdd(&h[absbits(x.w) >> 19], 1u);
    }
    if (blockIdx.x == 0 && (int)threadIdx.x < (n & 3)) {   // scalar tail
        u32 u = absbits(in[n4 * 4 + threadIdx.x]);
        atomicAdd(&h[u >> 19], 1u);
    }
    __syncthreads();
    u32* g = ws + H1_OFF + m * H1_BINS;
    for (int b = threadIdx.x; b < H1_BINS; b += blockDim.x)
        if (h[b]) atomicAdd(&g[b], h[b]);
    __syncthreads();
    if (threadIdx.x == 0) {
        __threadfence();
        u32 d = atomicAdd(&ws[CTR_OFF + m], 1u);
        isLast = (d == gridDim.x - 1) ? 1u : 0u;
    }
    __syncthreads();
    if (isLast) select_p1(g, (u32)(m ? K1 : K0), ws + SEL_OFF + m * SEL_WORDS, h);
}

// ---------- pass 2: pure filter+compact of absbits with prefix==p1 (no hist) ----------
__global__ void k_compact(const float* __restrict__ in0, const float* __restrict__ in1,
                          u32* __restrict__ sc0, u32* __restrict__ sc1,
                          int n0, int n1, u32* __restrict__ ws) {
    __shared__ u32 lbuf[CBUF];
    __shared__ u32 lcnt, gbase;
    const int m = blockIdx.y;
    const u32* in = (const u32*)(m ? in1 : in0);
    u32* scr = m ? sc1 : sc0;
    const int n = m ? n1 : n0;
    const int n4 = n >> 2;
    u32* sel = ws + SEL_OFF + m * SEL_WORDS;
    const u32 p1 = sel[0];
    u32* cnt = &sel[7];
    const int tid = threadIdx.x;
    if (tid == 0) lcnt = 0;
    __syncthreads();
    const uint4* v = (const uint4*)in;
    const int stride = gridDim.x * blockDim.x;
    const int i0 = blockIdx.x * blockDim.x + tid;
    const int nIter = (n4 + 8 * stride - 1) / (8 * stride);   // uniform across block
    for (int it = 0; it < nIter; ++it) {
        int i = i0 + it * 8 * stride;
        if (i + 7 * stride < n4) {
            uint4 x[8];
#pragma unroll
            for (int k = 0; k < 8; k++) x[k] = v[i + k * stride];
#pragma unroll
            for (int k = 0; k < 8; k++) {
                u32 a;
                a = absbits(x[k].x); if ((a >> 19) == p1) { u32 p = atomicAdd(&lcnt, 1u); lbuf[p] = a; }
                a = absbits(x[k].y); if ((a >> 19) == p1) { u32 p = atomicAdd(&lcnt, 1u); lbuf[p] = a; }
                a = absbits(x[k].z); if ((a >> 19) == p1) { u32 p = atomicAdd(&lcnt, 1u); lbuf[p] = a; }
                a = absbits(x[k].w); if ((a >> 19) == p1) { u32 p = atomicAdd(&lcnt, 1u); lbuf[p] = a; }
            }
        } else {
            for (int k = 0; k < 8; k++) {
                int ii = i + k * stride;
                if (ii < n4) {
                    uint4 x = v[ii];
                    u32 a;
                    a = absbits(x.x); if ((a >> 19) == p1) { u32 p = atomicAdd(&lcnt, 1u); lbuf[p] = a; }
                    a = absbits(x.y); if ((a >> 19) == p1) { u32 p = atomicAdd(&lcnt, 1u); lbuf[p] = a; }
                    a = absbits(x.z); if ((a >> 19) == p1) { u32 p = atomicAdd(&lcnt, 1u); lbuf[p] = a; }
                    a = absbits(x.w); if ((a >> 19) == p1) { u32 p = atomicAdd(&lcnt, 1u); lbuf[p] = a; }
                }
            }
        }
        __syncthreads();                       // appends done; lcnt stable & uniform
        if (lcnt >= CTHRESH) {                 // invariant: lcnt <= CTHRESH-1+8192 <= CBUF-1
            u32 c = lcnt;
            if (tid == 0) gbase = atomicAdd(cnt, c);
            __syncthreads();
            for (u32 j = tid; j < c; j += blockDim.x) scr[gbase + j] = lbuf[j];
            __syncthreads();
            if (tid == 0) lcnt = 0;
        }
        __syncthreads();                       // reset visible before next appends
    }
    if (blockIdx.x == 0 && tid < (n & 3)) {    // scalar tail: direct reservation
        u32 a = absbits(in[n4 * 4 + tid]);
        if ((a >> 19) == p1) { u32 p = atomicAdd(cnt, 1u); scr[p] = a; }
    }
    __syncthreads();
    u32 c = lcnt;                              // final flush
    if (c) {
        if (tid == 0) gbase = atomicAdd(cnt, c);
        __syncthreads();
        for (u32 j = tid; j < c; j += blockDim.x) scr[gbase + j] = lbuf[j];
    }
}

// ---------- two-level refinement on the compacted list; one block per matrix ----------
__global__ void k_select2(const u32* __restrict__ sc0, const u32* __restrict__ sc1,
                          int K0, int K1, u32* __restrict__ ws) {
    __shared__ u32 h[8192];
    __shared__ u32 sh[1024];
    __shared__ u32 g32[32];
    __shared__ u32 selb1, selk2;
    const int m = blockIdx.x;
    const u32* scr = m ? sc1 : sc0;
    u32* sel = ws + SEL_OFF + m * SEL_WORDS;
    const u32 E = sel[7];
    const u32 Krem = (u32)(m ? K1 : K0) - sel[2];
    const int tid = threadIdx.x;               // 1024 threads
    // ---- stage A: 8192-bin hist over suffix bits [18:6] ----
    for (int i = tid; i < 8192; i += 1024) h[i] = 0;
    __syncthreads();
    u32 e = (u32)tid;
    for (; e + 7u * 1024u < E; e += 8u * 1024u) {
        u32 a[8];
#pragma unroll
        for (int k = 0; k < 8; k++) a[k] = scr[e + (u32)k * 1024u];
#pragma unroll
        for (int k = 0; k < 8; k++) atomicAdd(&h[(a[k] & 0x7FFFFu) >> 6], 1u);
    }
    for (; e < E; e += 1024u) atomicAdd(&h[(scr[e] & 0x7FFFFu) >> 6], 1u);
    __syncthreads();
    // block-wide suffix-select over 8192 bins (chunk=8/thread, two-level scan)
    u32 loc[8];
    u32 s = 0;
    const int base = tid * 8;
#pragma unroll
    for (int i = 0; i < 8; i++) { loc[i] = h[base + i]; s += loc[i]; }
    sh[tid] = s;
    __syncthreads();
    if (tid < 32) { u32 t = 0; for (int j = 0; j < 32; j++) t += sh[tid * 32 + j]; g32[tid] = t; }
    __syncthreads();
    if (tid == 0) { u32 run = 0; for (int j = 31; j >= 0; j--) { u32 x = g32[j]; g32[j] = run; run += x; } }
    __syncthreads();
    u32 running = g32[tid >> 5];               // bins above my group
    for (int j = (tid | 31); j > tid; j--) running += sh[j];   // bins above me in group
#pragma unroll
    for (int b = 7; b >= 0; b--) {
        u32 c = loc[b];
        if (running < Krem && running + c >= Krem) {
            selb1 = (u32)(base + b);
            selk2 = Krem - running;            // ones still needed inside bin b1
        }
        running += c;
    }
    __syncthreads();
    const u32 b1 = selb1;
    const u32 K2 = selk2;
    // ---- stage B: 64-bin hist over suffix bits [5:0] among (suffix>>6)==b1 ----
    if (tid < 64) h[tid] = 0;
    __syncthreads();
    e = (u32)tid;
    for (; e + 7u * 1024u < E; e += 8u * 1024u) {
        u32 a[8];
#pragma unroll
        for (int k = 0; k < 8; k++) a[k] = scr[e + (u32)k * 1024u];
#pragma unroll
        for (int k = 0; k < 8; k++) {
            u32 sfx = a[k] & 0x7FFFFu;
            if ((sfx >> 6) == b1) atomicAdd(&h[sfx & 63u], 1u);
        }
    }
    for (; e < E; e += 1024u) {
        u32 sfx = scr[e] & 0x7FFFFu;
        if ((sfx >> 6) == b1) atomicAdd(&h[sfx & 63u], 1u);
    }
    __syncthreads();
    if (tid == 0) {
        u32 run = 0, t6 = 0, R = 0;
        for (int b = 63; b >= 0; b--) {
            u32 c = h[b];
            if (run < K2 && run + c >= K2) { t6 = (u32)b; R = K2 - run; }
            run += c;
        }
        u32 t19 = (b1 << 6) | t6;
        sel[3] = (sel[0] << 19) | t19;         // full 31-bit threshold value t
        sel[4] = R;                            // ones among exact ties at t
    }
}

// ---------- final mask write + collect tied indices (4-deep batched, NT stores) ----------
__global__ void k_mask(const float* __restrict__ in0, const float* __restrict__ in1,
                       float* __restrict__ out0, float* __restrict__ out1,
                       int n0, int n1, u32* __restrict__ ws) {
    const int m = blockIdx.y;
    const u32* in = (const u32*)(m ? in1 : in0);
    float* out = m ? out1 : out0;
    const int n = m ? n1 : n0;
    const int n4 = n >> 2;
    u32* sel = ws + SEL_OFF + m * SEL_WORDS;
    const u32 t = sel[3];
    u32* eq = ws + EQ_OFF + m * EQ_CAP;
    const uint4* v = (const uint4*)in;
    f32x4* o = (f32x4*)out;                    // native vector ptr (NT-store compatible)
    const int stride = gridDim.x * blockDim.x;
    int i = blockIdx.x * blockDim.x + threadIdx.x;
    for (; i + 3 * stride < n4; i += 4 * stride) {
        uint4 x[4];
#pragma unroll
        for (int k = 0; k < 4; k++) x[k] = v[i + k * stride];
#pragma unroll
        for (int k = 0; k < 4; k++) {
            u32 a0 = absbits(x[k].x), a1 = absbits(x[k].y), a2 = absbits(x[k].z), a3 = absbits(x[k].w);
            f32x4 r;
            r.x = (a0 > t) ? 1.0f : 0.0f;
            r.y = (a1 > t) ? 1.0f : 0.0f;
            r.z = (a2 > t) ? 1.0f : 0.0f;
            r.w = (a3 > t) ? 1.0f : 0.0f;
            __builtin_nontemporal_store(r, &o[i + k * stride]);   // streamed output: keep out of L2
            int ib = 4 * (i + k * stride);
            if (a0 == t) { u32 p = atomicAdd(&sel[6], 1u); if (p < EQ_CAP) eq[p] = (u32)(ib + 0); }
            if (a1 == t) { u32 p = atomicAdd(&sel[6], 1u); if (p < EQ_CAP) eq[p] = (u32)(ib + 1); }
            if (a2 == t) { u32 p = atomicAdd(&sel[6], 1u); if (p < EQ_CAP) eq[p] = (u32)(ib + 2); }
            if (a3 == t) { u32 p = atomicAdd(&sel[6], 1u); if (p < EQ_CAP) eq[p] = (u32)(ib + 3); }
        }
    }
    for (; i < n4; i += stride) {
        uint4 x = v[i];
        u32 a0 = absbits(x.x), a1 = absbits(x.y), a2 = absbits(x.z), a3 = absbits(x.w);
        f32x4 r;
        r.x = (a0 > t) ? 1.0f : 0.0f;
        r.y = (a1 > t) ? 1.0f : 0.0f;
        r.z = (a2 > t) ? 1.0f : 0.0f;
        r.w = (a3 > t) ? 1.0f : 0.0f;
        __builtin_nontemporal_store(r, &o[i]);
        if (a0 == t) { u32 p = atomicAdd(&sel[6], 1u); if (p < EQ_CAP) eq[p] = (u32)(4 * i + 0); }
        if (a1 == t) { u32 p = atomicAdd(&sel[6], 1u); if (p < EQ_CAP) eq[p] = (u32)(4 * i + 1); }
        if (a2 == t) { u32 p = atomicAdd(&sel[6], 1u); if (p < EQ_CAP) eq[p] = (u32)(4 * i + 2); }
        if (a3 == t) { u32 p = atomicAdd(&sel[6], 1u); if (p < EQ_CAP) eq[p] = (u32)(4 * i + 3); }
    }
    if (blockIdx.x == 0 && (int)threadIdx.x < (n & 3)) {
        int idx = n4 * 4 + threadIdx.x;
        u32 a = absbits(in[idx]);
        out[idx] = (a > t) ? 1.0f : 0.0f;
        if (a == t) { u32 p = atomicAdd(&sel[6], 1u); if (p < EQ_CAP) eq[p] = (u32)idx; }
    }
}

// ---------- tie resolution: stable ascending argsort keeps later indices on top ----------
__global__ void k_tie(float* __restrict__ out0, float* __restrict__ out1, u32* __restrict__ ws) {
    const int m = blockIdx.x;
    float* out = m ? out1 : out0;
    u32* sel = ws + SEL_OFF + m * SEL_WORDS;
    u32 E = sel[6]; if (E > EQ_CAP) E = EQ_CAP;
    const u32 R = sel[4];
    const u32* eq = ws + EQ_OFF + m * EQ_CAP;
    for (u32 e = threadIdx.x; e < E; e += blockDim.x) {
        u32 idx = eq[e];
        u32 cnt = 0;
        for (u32 e2 = 0; e2 < E; e2++) cnt += (eq[e2] > idx) ? 1u : 0u;
        if (cnt < R) out[idx] = 1.0f;   // the R tied elements with largest indices get 1
    }
}

extern "C" void kernel_launch(void* const* d_in, const int* in_sizes, int n_in,
                              void* d_out, int out_size, void* d_ws, size_t ws_size,
                              hipStream_t stream) {
    const float* in0 = (const float*)d_in[0];
    const float* in1 = (const float*)d_in[1];
    const int n0 = in_sizes[0];
    const int n1 = in_sizes[1];
    float* out0 = (float*)d_out;
    float* out1 = out0 + n0;
    u32* ws = (u32*)d_ws;

    // Faithful to int((1.0 - k) * n) in double precision: j = 15,099,494 for n = 16,777,216
    const double k = 0.1;
    const int j0 = (int)((1.0 - k) * (double)n0);
    const int j1 = (int)((1.0 - k) * (double)n1);
    const int K0 = n0 - j0;   // number of ones = 1,677,722
    const int K1 = n1 - j1;

    // Compaction scratch lives in the output buffer: consumed by k_select2 strictly
    // before k_mask overwrites it. Capacity = n words per matrix (cannot overflow).
    u32* scr0 = (u32*)out0;
    u32* scr1 = (u32*)out1;

    (void)hipMemsetAsync(ws, 0, ZERO_WORDS * sizeof(u32), stream);

    k_hist1 <<<dim3(1024, 2), 256, 0, stream>>>(in0, in1, n0, n1, K0, K1, ws);
    k_compact<<<dim3(1024, 2), 256, 0, stream>>>(in0, in1, scr0, scr1, n0, n1, ws);
    k_select2<<<2, 1024, 0, stream>>>(scr0, scr1, K0, K1, ws);
    k_mask   <<<dim3(1024, 2), 256, 0, stream>>>(in0, in1, out0, out1, n0, n1, ws);
    k_tie    <<<2, 256, 0, stream>>>(out0, out1, ws);
}